// Round 8
// baseline (398.739 us; speedup 1.0000x reference)
//
#include <hip/hip_runtime.h>
#include <hip/hip_bf16.h>

typedef __bf16 bf16x8 __attribute__((ext_vector_type(8)));
typedef int   i32x8 __attribute__((ext_vector_type(8)));
typedef float f32x4 __attribute__((ext_vector_type(4)));

#define KDIM 512
#define NDIM 1024
#define DDIM 256
#define TDIM 512
#define MDIM 2048
#define NROWS 16384          // B*T type_flat rows
#define NEGV -1e10f
#define NLM 128              // lm blocks fused at the front of the main grid

__device__ __forceinline__ unsigned short f2b(float f) {
    unsigned int u = __builtin_bit_cast(unsigned int, f);
    u += 0x7fffu + ((u >> 16) & 1u);   // RNE
    return (unsigned short)(u >> 16);
}

typedef const __attribute__((address_space(1))) unsigned int* gas_p;
typedef __attribute__((address_space(3))) unsigned int* las_p;
__device__ __forceinline__ void gl2lds16(const void* g, void* l) {
    __builtin_amdgcn_global_load_lds((gas_p)g, (las_p)l, 16, 0, 0);
}

// ---------------------------------------------------------------------------
// prep_all: one launch, three roles by blockIdx.  (unchanged from R6/R7)
// ---------------------------------------------------------------------------
__global__ void prep_all(const float* __restrict__ tok,
                         const float* __restrict__ Wg,
                         const float* __restrict__ Wv,
                         const int* __restrict__ bp,
                         unsigned short* __restrict__ tfb,
                         unsigned char* __restrict__ tf8,
                         unsigned char* __restrict__ wg8,
                         unsigned char* __restrict__ wv8,
                         int* __restrict__ counts,
                         unsigned short* __restrict__ lists) {
    const int bid = blockIdx.x;
    const int tid = threadIdx.x;
    if (bid < 4096) {
        int g = (bid * 256 + tid) * 4;
        int i = g >> 8, c = g & 255;
        float4 v = *(const float4*)(tok + (size_t)i * 1024 + c);
        tfb[g + 0] = f2b(v.x);
        tfb[g + 1] = f2b(v.y);
        tfb[g + 2] = f2b(v.z);
        tfb[g + 3] = f2b(v.w);
        unsigned int p = (unsigned int)__builtin_amdgcn_cvt_pk_fp8_f32(v.x, v.y, 0, 0);
        p = (unsigned int)__builtin_amdgcn_cvt_pk_fp8_f32(v.z, v.w, (int)p, 1);
        *(unsigned int*)(tf8 + g) = p;
    } else if (bid < 4608) {
        __shared__ float tg[32][33];
        __shared__ float tv[32][33];
        int pb = bid - 4096;
        int n0 = (pb & 31) * 32, k0 = (pb >> 5) * 32;
        {
            int kk = tid >> 3, nn = (tid & 7) * 4;
            float4 g = *(const float4*)(Wg + (size_t)(k0 + kk) * NDIM + n0 + nn);
            float4 v = *(const float4*)(Wv + (size_t)(k0 + kk) * NDIM + n0 + nn);
            tg[kk][nn] = g.x; tg[kk][nn + 1] = g.y; tg[kk][nn + 2] = g.z; tg[kk][nn + 3] = g.w;
            tv[kk][nn] = v.x; tv[kk][nn + 1] = v.y; tv[kk][nn + 2] = v.z; tv[kk][nn + 3] = v.w;
        }
        __syncthreads();
        int nn2 = tid >> 3, kk2 = (tid & 7) * 4;
        unsigned int pg = (unsigned int)__builtin_amdgcn_cvt_pk_fp8_f32(
            tg[kk2][nn2], tg[kk2 + 1][nn2], 0, 0);
        pg = (unsigned int)__builtin_amdgcn_cvt_pk_fp8_f32(
            tg[kk2 + 2][nn2], tg[kk2 + 3][nn2], (int)pg, 1);
        unsigned int pv = (unsigned int)__builtin_amdgcn_cvt_pk_fp8_f32(
            tv[kk2][nn2], tv[kk2 + 1][nn2], 0, 0);
        pv = (unsigned int)__builtin_amdgcn_cvt_pk_fp8_f32(
            tv[kk2 + 2][nn2], tv[kk2 + 3][nn2], (int)pv, 1);
        *(unsigned int*)(wg8 + (size_t)(n0 + nn2) * KDIM + k0 + kk2) = pg;
        *(unsigned int*)(wv8 + (size_t)(n0 + nn2) * KDIM + k0 + kk2) = pv;
    } else {
        __shared__ int c[32];
        if (tid < 32) c[tid] = 0;
        __syncthreads();
        for (int m = tid; m < MDIM; m += 256) {
            int b = bp[m];
            int pos = atomicAdd(&c[b], 1);
            lists[b * MDIM + pos] = (unsigned short)m;
        }
        __syncthreads();
        if (tid < 32) counts[tid] = c[tid];
    }
}

// ---------------------------------------------------------------------------
// fused_main: blocks [0,NLM) = lm_preds gather-GEMM (unchanged, proven);
// blocks [NLM,..) = lemma MX-fp8 dual GEMM, BARRIER-FREE K-loop:
//   - A (gathered edges, 128 x 512 B fp8) persistent in 64 KB LDS (R7-proven)
//   - B fragments loaded DIRECTLY global->VGPR (weights are 1 MB, L2-hot;
//     32 B/lane contiguous) — no sB, no __syncthreads in the 64-step loop,
//     so prefetch stays in flight across steps (vmcnt(N), not barrier-drain)
//   - wave tile 64m x 32n dual-acc = 64 acc regs
// LDS = 64 KB A + 1 KB red = 65 KB -> 2 blocks/CU.
// ---------------------------------------------------------------------------
__launch_bounds__(256, 2)
__global__ void fused_main(const unsigned char* __restrict__ tf8,
                           const unsigned char* __restrict__ wg8,
                           const unsigned char* __restrict__ wv8,
                           const float* __restrict__ Wo,
                           const int* __restrict__ scope,
                           const int* __restrict__ goal,
                           float* __restrict__ outLem, int E,
                           const float* __restrict__ tok,
                           const unsigned short* __restrict__ tfb,
                           const int* __restrict__ lmi,
                           const int* __restrict__ counts,
                           const unsigned short* __restrict__ lists,
                           const int* __restrict__ tpm,
                           float* __restrict__ outP) {
    __shared__ unsigned char sA[128 * 512];   // 64 KB: seg = row*2+half, 256 B each
    __shared__ float sRed[256];               // 1 KB

    const int tid = threadIdx.x;
    const int lane = tid & 63;
    const int w = tid >> 6;
    const int col = lane & 15;
    const int q = lane >> 4;

    if ((int)blockIdx.x < NLM) {
        // ---------------- lm_preds gather-GEMM (R5/R6-proven) ----------------
        const int lb = blockIdx.x;
        const int b = lb & 31;
        const int t0 = (lb >> 5) * 128;
        const int cnt = counts[b];
        for (int mt = w * 16; mt < cnt; mt += 64) {
            int mc = mt + col;
            int aid = lists[b * MDIM + (mc < cnt ? mc : cnt - 1)];
            const float* arow = tok + (size_t)lmi[aid] * DDIM;
            bf16x8 af[8];
#pragma unroll
            for (int k = 0; k < 8; k++) {
                float4 lo = *(const float4*)(arow + k * 32 + q * 8);
                float4 hi = *(const float4*)(arow + k * 32 + q * 8 + 4);
                uint4 p;
                p.x = f2b(lo.x) | ((unsigned int)f2b(lo.y) << 16);
                p.y = f2b(lo.z) | ((unsigned int)f2b(lo.w) << 16);
                p.z = f2b(hi.x) | ((unsigned int)f2b(hi.y) << 16);
                p.w = f2b(hi.z) | ((unsigned int)f2b(hi.w) << 16);
                af[k] = __builtin_bit_cast(bf16x8, p);
            }
            int gm[4];
#pragma unroll
            for (int r = 0; r < 4; r++) {
                int mrow = mt + q * 4 + r;
                gm[r] = (mrow < cnt) ? (int)lists[b * MDIM + mrow] : -1;
            }
#pragma unroll
            for (int ntile = 0; ntile < 8; ntile++) {
                int t = t0 + ntile * 16 + col;
                const unsigned short* brow = tfb + (size_t)(b * TDIM + t) * DDIM;
                f32x4 acc = (f32x4){0.f, 0.f, 0.f, 0.f};
#pragma unroll
                for (int k = 0; k < 8; k++) {
                    bf16x8 bf = __builtin_bit_cast(bf16x8,
                        *(const uint4*)(brow + k * 32 + q * 8));
                    acc = __builtin_amdgcn_mfma_f32_16x16x32_bf16(af[k], bf, acc, 0, 0, 0);
                }
                int pmv = tpm[b * TDIM + t];
#pragma unroll
                for (int r = 0; r < 4; r++) {
                    if (gm[r] >= 0)
                        outP[(size_t)gm[r] * TDIM + t] = pmv ? acc[r] : NEGV;
                }
            }
        }
        return;
    }

    // ------------------------- lemma MX-fp8 GEMM -------------------------
    const int bx = blockIdx.x - NLM;
    const int etile = bx * 128;
    const int wm = w & 1;      // m-half (64 rows)
    const int wn = w >> 1;     // n-half (32 cols of the 64-wide n-tile)

    // ---- stage A once (R7-proven): 256 segs x 256 B; 4 segs/instruction ----
#pragma unroll
    for (int i = 0; i < 16; i++) {
        int s0 = i * 16 + w * 4;
        int seg = s0 + (lane >> 4);
        int row = seg >> 1;
        int h = seg & 1;
        int e = etile + row;
        int id = (e < E) ? (h ? goal[e] : scope[e]) : 0;
        int u = lane & 15;
        int usw = (u & 8) | ((u & 7) ^ (row & 7));
        gl2lds16(tf8 + (size_t)id * DDIM + usw * 16, &sA[s0 * 256]);
    }
    __syncthreads();   // the ONLY staging barrier

    float lem[16];
#pragma unroll
    for (int i = 0; i < 16; i++) lem[i] = 0.f;

    // per-lane B base: row (wn*32 + col), bytes q*32 within each 128-B chunk
    const unsigned char* bgbase = wg8 + (size_t)(wn * 32 + col) * KDIM + q * 32;
    const unsigned char* bvbase = wv8 + (size_t)(wn * 32 + col) * KDIM + q * 32;

    for (int nt = 0; nt < 16; nt++) {
        const int n0 = nt * 64;
        const size_t nOff = (size_t)n0 * KDIM;
        f32x4 accG[4][2], accV[4][2];
#pragma unroll
        for (int mi = 0; mi < 4; mi++)
#pragma unroll
            for (int ni = 0; ni < 2; ni++) {
                accG[mi][ni] = (f32x4){0.f, 0.f, 0.f, 0.f};
                accV[mi][ni] = (f32x4){0.f, 0.f, 0.f, 0.f};
            }
#pragma unroll
        for (int kc = 0; kc < 4; kc++) {
            // B fragments: direct global->VGPR, 32 B/lane (2 x dwordx4)
            uint4 glo[2], ghi[2], vlo[2], vhi[2];
#pragma unroll
            for (int ni = 0; ni < 2; ni++) {
                const unsigned char* pg = bgbase + nOff + (size_t)ni * 16 * KDIM + kc * 128;
                const unsigned char* pv = bvbase + nOff + (size_t)ni * 16 * KDIM + kc * 128;
                glo[ni] = *(const uint4*)pg;
                ghi[ni] = *(const uint4*)(pg + 16);
                vlo[ni] = *(const uint4*)pv;
                vhi[ni] = *(const uint4*)(pv + 16);
            }
            // A fragments from persistent LDS (R7-proven swizzle)
            i32x8 af[4];
#pragma unroll
            for (int mi = 0; mi < 4; mi++) {
                int row = wm * 64 + mi * 16 + col;
                int r7 = row & 7;
                const unsigned char* base = &sA[row * 512 + (kc >> 1) * 256 + (kc & 1) * 128];
                uint4 lo = *(const uint4*)(base + (((2 * q) ^ r7) * 16));
                uint4 hi = *(const uint4*)(base + (((2 * q + 1) ^ r7) * 16));
                af[mi] = (i32x8){(int)lo.x, (int)lo.y, (int)lo.z, (int)lo.w,
                                 (int)hi.x, (int)hi.y, (int)hi.z, (int)hi.w};
            }
#pragma unroll
            for (int ni = 0; ni < 2; ni++) {
                i32x8 bg = (i32x8){(int)glo[ni].x, (int)glo[ni].y, (int)glo[ni].z, (int)glo[ni].w,
                                   (int)ghi[ni].x, (int)ghi[ni].y, (int)ghi[ni].z, (int)ghi[ni].w};
                i32x8 bv = (i32x8){(int)vlo[ni].x, (int)vlo[ni].y, (int)vlo[ni].z, (int)vlo[ni].w,
                                   (int)vhi[ni].x, (int)vhi[ni].y, (int)vhi[ni].z, (int)vhi[ni].w};
#pragma unroll
                for (int mi = 0; mi < 4; mi++) {
                    accG[mi][ni] = __builtin_amdgcn_mfma_scale_f32_16x16x128_f8f6f4(
                        af[mi], bg, accG[mi][ni], 0, 0, 0, 0x7F7F7F7F, 0, 0x7F7F7F7F);
                    accV[mi][ni] = __builtin_amdgcn_mfma_scale_f32_16x16x128_f8f6f4(
                        af[mi], bv, accV[mi][ni], 0, 0, 0, 0x7F7F7F7F, 0, 0x7F7F7F7F);
                }
            }
        }
        // epilogue: lem += silu(G) * V * Wo[n]. C/D: M=q*4+r, N=col.
#pragma unroll
        for (int ni = 0; ni < 2; ni++) {
            float wo = Wo[n0 + wn * 32 + ni * 16 + col];
#pragma unroll
            for (int mi = 0; mi < 4; mi++)
#pragma unroll
                for (int r = 0; r < 4; r++) {
                    float g = accG[mi][ni][r];
                    float v = accV[mi][ni][r];
                    float s = g / (1.f + __expf(-g));
                    lem[mi * 4 + r] += s * v * wo;
                }
        }
    }
    // reduce across 16 N-cols, then across the 2 n-waves
#pragma unroll
    for (int i = 0; i < 16; i++) {
        float v = lem[i];
        for (int off = 8; off > 0; off >>= 1) v += __shfl_xor(v, off, 16);
        if (col == 0) {
            int row = wm * 64 + (i >> 2) * 16 + q * 4 + (i & 3);
            sRed[wn * 128 + row] = v;
        }
    }
    __syncthreads();
    if (tid < 128) {
        int e = etile + tid;
        if (e < E) outLem[e] = sRed[tid] + sRed[128 + tid];
    }
}

extern "C" void kernel_launch(void* const* d_in, const int* in_sizes, int n_in,
                              void* d_out, int out_size, void* d_ws, size_t ws_size,
                              hipStream_t stream) {
    const float* tok = (const float*)d_in[0];
    const float* Wg  = (const float*)d_in[1];
    const float* Wv  = (const float*)d_in[2];
    const float* Wo  = (const float*)d_in[3];
    const int* edge = (const int*)d_in[4];
    const int* lmi  = (const int*)d_in[5];
    const int* bp   = (const int*)d_in[6];
    const int* tpm  = (const int*)d_in[7];
    const int E = in_sizes[4] / 2;           // 100000
    float* out = (float*)d_out;

    // workspace layout (~13.2 MB)
    unsigned short* tfb = (unsigned short*)d_ws;                        // 8 MB
    unsigned char*  tf8 = (unsigned char*)(tfb + (size_t)NROWS * DDIM); // 4 MB
    unsigned char*  wg8 = tf8 + (size_t)NROWS * DDIM;                   // 512 KB
    unsigned char*  wv8 = wg8 + (size_t)NDIM * KDIM;                    // 512 KB
    int* counts = (int*)(wv8 + (size_t)NDIM * KDIM);                    // 128 B
    unsigned short* lists = (unsigned short*)(counts + 32);             // 128 KB

    prep_all<<<dim3(4609), dim3(256), 0, stream>>>(
        tok, Wg, Wv, bp, tfb, tf8, wg8, wv8, counts, lists);
    int nLemBlocks = (E + 127) / 128;        // 782
    fused_main<<<dim3(NLM + nLemBlocks), dim3(256), 0, stream>>>(
        tf8, wg8, wv8, Wo, edge, edge + E, out, E,
        tok, tfb, lmi, counts, lists, tpm, out + E);
}

// Round 9
// 357.738 us; speedup vs baseline: 1.1146x; 1.1146x over previous
//
#include <hip/hip_runtime.h>
#include <hip/hip_bf16.h>

typedef __bf16 bf16x8 __attribute__((ext_vector_type(8)));
typedef int   i32x8 __attribute__((ext_vector_type(8)));
typedef float f32x4 __attribute__((ext_vector_type(4)));

#define KDIM 512
#define NDIM 1024
#define DDIM 256
#define TDIM 512
#define MDIM 2048
#define NROWS 16384          // B*T type_flat rows
#define NEGV -1e10f
#define NLM 128              // lm blocks fused at the front of the main grid

__device__ __forceinline__ unsigned short f2b(float f) {
    unsigned int u = __builtin_bit_cast(unsigned int, f);
    u += 0x7fffu + ((u >> 16) & 1u);   // RNE
    return (unsigned short)(u >> 16);
}

typedef const __attribute__((address_space(1))) unsigned int* gas_p;
typedef __attribute__((address_space(3))) unsigned int* las_p;
__device__ __forceinline__ void gl2lds16(const void* g, void* l) {
    __builtin_amdgcn_global_load_lds((gas_p)g, (las_p)l, 16, 0, 0);
}

// ---------------------------------------------------------------------------
// prep_all: one launch, three roles by blockIdx.  (unchanged from R6/R7)
// ---------------------------------------------------------------------------
__global__ void prep_all(const float* __restrict__ tok,
                         const float* __restrict__ Wg,
                         const float* __restrict__ Wv,
                         const int* __restrict__ bp,
                         unsigned short* __restrict__ tfb,
                         unsigned char* __restrict__ tf8,
                         unsigned char* __restrict__ wg8,
                         unsigned char* __restrict__ wv8,
                         int* __restrict__ counts,
                         unsigned short* __restrict__ lists) {
    const int bid = blockIdx.x;
    const int tid = threadIdx.x;
    if (bid < 4096) {
        int g = (bid * 256 + tid) * 4;
        int i = g >> 8, c = g & 255;
        float4 v = *(const float4*)(tok + (size_t)i * 1024 + c);
        tfb[g + 0] = f2b(v.x);
        tfb[g + 1] = f2b(v.y);
        tfb[g + 2] = f2b(v.z);
        tfb[g + 3] = f2b(v.w);
        unsigned int p = (unsigned int)__builtin_amdgcn_cvt_pk_fp8_f32(v.x, v.y, 0, 0);
        p = (unsigned int)__builtin_amdgcn_cvt_pk_fp8_f32(v.z, v.w, (int)p, 1);
        *(unsigned int*)(tf8 + g) = p;
    } else if (bid < 4608) {
        __shared__ float tg[32][33];
        __shared__ float tv[32][33];
        int pb = bid - 4096;
        int n0 = (pb & 31) * 32, k0 = (pb >> 5) * 32;
        {
            int kk = tid >> 3, nn = (tid & 7) * 4;
            float4 g = *(const float4*)(Wg + (size_t)(k0 + kk) * NDIM + n0 + nn);
            float4 v = *(const float4*)(Wv + (size_t)(k0 + kk) * NDIM + n0 + nn);
            tg[kk][nn] = g.x; tg[kk][nn + 1] = g.y; tg[kk][nn + 2] = g.z; tg[kk][nn + 3] = g.w;
            tv[kk][nn] = v.x; tv[kk][nn + 1] = v.y; tv[kk][nn + 2] = v.z; tv[kk][nn + 3] = v.w;
        }
        __syncthreads();
        int nn2 = tid >> 3, kk2 = (tid & 7) * 4;
        unsigned int pg = (unsigned int)__builtin_amdgcn_cvt_pk_fp8_f32(
            tg[kk2][nn2], tg[kk2 + 1][nn2], 0, 0);
        pg = (unsigned int)__builtin_amdgcn_cvt_pk_fp8_f32(
            tg[kk2 + 2][nn2], tg[kk2 + 3][nn2], (int)pg, 1);
        unsigned int pv = (unsigned int)__builtin_amdgcn_cvt_pk_fp8_f32(
            tv[kk2][nn2], tv[kk2 + 1][nn2], 0, 0);
        pv = (unsigned int)__builtin_amdgcn_cvt_pk_fp8_f32(
            tv[kk2 + 2][nn2], tv[kk2 + 3][nn2], (int)pv, 1);
        *(unsigned int*)(wg8 + (size_t)(n0 + nn2) * KDIM + k0 + kk2) = pg;
        *(unsigned int*)(wv8 + (size_t)(n0 + nn2) * KDIM + k0 + kk2) = pv;
    } else {
        __shared__ int c[32];
        if (tid < 32) c[tid] = 0;
        __syncthreads();
        for (int m = tid; m < MDIM; m += 256) {
            int b = bp[m];
            int pos = atomicAdd(&c[b], 1);
            lists[b * MDIM + pos] = (unsigned short)m;
        }
        __syncthreads();
        if (tid < 32) counts[tid] = c[tid];
    }
}

// ---------------------------------------------------------------------------
// fused_main: blocks [0,NLM) = lm_preds gather-GEMM (unchanged, proven);
// blocks [NLM,..) = lemma MX-fp8 dual GEMM, PIPELINED:
//   - M=64 edges/block; A fragments (16 x i32x8 = 128 VGPRs) loaded ONCE from
//     global into registers (unroll-by-4 keeps indices static -> no scratch)
//   - B staged into LDS in FRAGMENT ORDER (wave-private regions, DMA writes
//     exactly in read order) -> B reads are base+lane*16, conflict-free,
//     zero address math.  R7's B-read swizzle had quad=slot collisions
//     (12.8M bank-conflict cycles).
//   - ONE barrier per step: sync -> issue DMA(s+1) -> compute(s).  The
//     vmcnt(0) drain at the next barrier lands after a full compute step,
//     so DMA latency is overlapped (unlike the 2-barrier m97 shape).
// LDS = 32 KB B double-buffer + 1 KB reduce -> VGPR-bound 2 blocks/CU.
// ---------------------------------------------------------------------------
__launch_bounds__(256, 2)
__global__ void fused_main(const unsigned char* __restrict__ tf8,
                           const unsigned char* __restrict__ wg8,
                           const unsigned char* __restrict__ wv8,
                           const float* __restrict__ Wo,
                           const int* __restrict__ scope,
                           const int* __restrict__ goal,
                           float* __restrict__ outLem, int E,
                           const float* __restrict__ tok,
                           const unsigned short* __restrict__ tfb,
                           const int* __restrict__ lmi,
                           const int* __restrict__ counts,
                           const unsigned short* __restrict__ lists,
                           const int* __restrict__ tpm,
                           float* __restrict__ outP) {
    __shared__ unsigned char sB[2 * 16384];   // 32 KB: [buf][wave][arr][half][lane*16]
    __shared__ float sRed[256];               // 1 KB

    const int tid = threadIdx.x;
    const int lane = tid & 63;
    const int w = tid >> 6;
    const int col = lane & 15;
    const int q = lane >> 4;

    if ((int)blockIdx.x < NLM) {
        // ---------------- lm_preds gather-GEMM (R5/R6-proven) ----------------
        const int lb = blockIdx.x;
        const int b = lb & 31;
        const int t0 = (lb >> 5) * 128;
        const int cnt = counts[b];
        for (int mt = w * 16; mt < cnt; mt += 64) {
            int mc = mt + col;
            int aid = lists[b * MDIM + (mc < cnt ? mc : cnt - 1)];
            const float* arow = tok + (size_t)lmi[aid] * DDIM;
            bf16x8 af[8];
#pragma unroll
            for (int k = 0; k < 8; k++) {
                float4 lo = *(const float4*)(arow + k * 32 + q * 8);
                float4 hi = *(const float4*)(arow + k * 32 + q * 8 + 4);
                uint4 p;
                p.x = f2b(lo.x) | ((unsigned int)f2b(lo.y) << 16);
                p.y = f2b(lo.z) | ((unsigned int)f2b(lo.w) << 16);
                p.z = f2b(hi.x) | ((unsigned int)f2b(hi.y) << 16);
                p.w = f2b(hi.z) | ((unsigned int)f2b(hi.w) << 16);
                af[k] = __builtin_bit_cast(bf16x8, p);
            }
            int gm[4];
#pragma unroll
            for (int r = 0; r < 4; r++) {
                int mrow = mt + q * 4 + r;
                gm[r] = (mrow < cnt) ? (int)lists[b * MDIM + mrow] : -1;
            }
#pragma unroll
            for (int ntile = 0; ntile < 8; ntile++) {
                int t = t0 + ntile * 16 + col;
                const unsigned short* brow = tfb + (size_t)(b * TDIM + t) * DDIM;
                f32x4 acc = (f32x4){0.f, 0.f, 0.f, 0.f};
#pragma unroll
                for (int k = 0; k < 8; k++) {
                    bf16x8 bf = __builtin_bit_cast(bf16x8,
                        *(const uint4*)(brow + k * 32 + q * 8));
                    acc = __builtin_amdgcn_mfma_f32_16x16x32_bf16(af[k], bf, acc, 0, 0, 0);
                }
                int pmv = tpm[b * TDIM + t];
#pragma unroll
                for (int r = 0; r < 4; r++) {
                    if (gm[r] >= 0)
                        outP[(size_t)gm[r] * TDIM + t] = pmv ? acc[r] : NEGV;
                }
            }
        }
        return;
    }

    // ------------------------- lemma MX-fp8 GEMM -------------------------
    const int bx = blockIdx.x - NLM;
    const int etile = bx * 64;

    // ---- A fragments: direct global -> 128 VGPRs (once per block) ----
    // af[kc][mi]: lane (col,q) holds bytes q*32..q*32+31 of k-chunk kc for
    // edge row mi*16+col.  kc 0,1 = scope halves; 2,3 = goal halves.
    i32x8 af[4][4];
#pragma unroll
    for (int mi = 0; mi < 4; mi++) {
        int e = etile + mi * 16 + col;
        int idS = (e < E) ? scope[e] : 0;
        int idG = (e < E) ? goal[e] : 0;
#pragma unroll
        for (int kc = 0; kc < 4; kc++) {
            int id = (kc < 2) ? idS : idG;
            const unsigned char* src = tf8 + (size_t)id * DDIM + (kc & 1) * 128 + q * 32;
            uint4 lo = *(const uint4*)src;
            uint4 hi = *(const uint4*)(src + 16);
            af[kc][mi] = (i32x8){(int)lo.x, (int)lo.y, (int)lo.z, (int)lo.w,
                                 (int)hi.x, (int)hi.y, (int)hi.z, (int)hi.w};
        }
    }

    // ---- B staging: fragment-ordered wave-private regions ----
    // region byte offset = buf*16384 + w*4096 + a*2048 + h*1024 + lane*16
    // lane holds bytes (q*32 + h*16 .. +16) of row (n0 + w*16 + col), chunk kc.
    const int rowOff = w * 16 + col;          // B row this lane stages/reads
    const int kByte = q * 32;
#define STAGE_B(s, buf)                                                        \
    {                                                                          \
        int nt_ = (s) >> 2, kc_ = (s) & 3;                                     \
        const unsigned char* g_ = wg8 +                                        \
            (size_t)(nt_ * 64 + rowOff) * KDIM + kc_ * 128 + kByte;            \
        const unsigned char* v_ = wv8 +                                        \
            (size_t)(nt_ * 64 + rowOff) * KDIM + kc_ * 128 + kByte;            \
        unsigned char* d_ = &sB[(buf) * 16384 + w * 4096];                     \
        gl2lds16(g_,      d_);                                                 \
        gl2lds16(g_ + 16, d_ + 1024);                                          \
        gl2lds16(v_,      d_ + 2048);                                          \
        gl2lds16(v_ + 16, d_ + 3072);                                          \
    }

    STAGE_B(0, 0)

    float lem[16];
#pragma unroll
    for (int i = 0; i < 16; i++) lem[i] = 0.f;
    f32x4 accG[4], accV[4];
#pragma unroll
    for (int mi = 0; mi < 4; mi++) {
        accG[mi] = (f32x4){0.f, 0.f, 0.f, 0.f};
        accV[mi] = (f32x4){0.f, 0.f, 0.f, 0.f};
    }

#pragma unroll 4
    for (int s = 0; s < 64; s++) {
        __syncthreads();                     // drains DMA(s) [+ compute(s-1) done]
        if (s < 63) STAGE_B(s + 1, (s + 1) & 1)
        const int kc = s & 3;                // static under unroll-4
        const unsigned char* rb = &sB[(s & 1) * 16384 + w * 4096 + lane * 16];
        uint4 gl = *(const uint4*)rb;
        uint4 gh = *(const uint4*)(rb + 1024);
        uint4 vl = *(const uint4*)(rb + 2048);
        uint4 vh = *(const uint4*)(rb + 3072);
        i32x8 bg = (i32x8){(int)gl.x, (int)gl.y, (int)gl.z, (int)gl.w,
                           (int)gh.x, (int)gh.y, (int)gh.z, (int)gh.w};
        i32x8 bv = (i32x8){(int)vl.x, (int)vl.y, (int)vl.z, (int)vl.w,
                           (int)vh.x, (int)vh.y, (int)vh.z, (int)vh.w};
#pragma unroll
        for (int mi = 0; mi < 4; mi++) {
            accG[mi] = __builtin_amdgcn_mfma_scale_f32_16x16x128_f8f6f4(
                af[kc][mi], bg, accG[mi], 0, 0, 0, 0x7F7F7F7F, 0, 0x7F7F7F7F);
            accV[mi] = __builtin_amdgcn_mfma_scale_f32_16x16x128_f8f6f4(
                af[kc][mi], bv, accV[mi], 0, 0, 0, 0x7F7F7F7F, 0, 0x7F7F7F7F);
        }
        if (kc == 3) {
            // epilogue for n-tile nt = s>>2: lem += silu(G)*V*Wo[n]
            float wo = Wo[(s >> 2) * 64 + w * 16 + col];
#pragma unroll
            for (int mi = 0; mi < 4; mi++)
#pragma unroll
                for (int r = 0; r < 4; r++) {
                    float g = accG[mi][r];
                    float v = accV[mi][r];
                    float sg = g / (1.f + __expf(-g));
                    lem[mi * 4 + r] += sg * v * wo;
                    accG[mi][r] = 0.f;
                    accV[mi][r] = 0.f;
                }
        }
    }

    // reduce across the 16 N-cols, then across the 4 n-waves
#pragma unroll
    for (int i = 0; i < 16; i++) {
        float v = lem[i];
        for (int off = 8; off > 0; off >>= 1) v += __shfl_xor(v, off, 16);
        if (col == 0) {
            int row = (i >> 2) * 16 + q * 4 + (i & 3);
            sRed[w * 64 + row] = v;
        }
    }
    __syncthreads();
    if (tid < 64) {
        int e = etile + tid;
        if (e < E)
            outLem[e] = sRed[tid] + sRed[64 + tid] + sRed[128 + tid] + sRed[192 + tid];
    }
}

extern "C" void kernel_launch(void* const* d_in, const int* in_sizes, int n_in,
                              void* d_out, int out_size, void* d_ws, size_t ws_size,
                              hipStream_t stream) {
    const float* tok = (const float*)d_in[0];
    const float* Wg  = (const float*)d_in[1];
    const float* Wv  = (const float*)d_in[2];
    const float* Wo  = (const float*)d_in[3];
    const int* edge = (const int*)d_in[4];
    const int* lmi  = (const int*)d_in[5];
    const int* bp   = (const int*)d_in[6];
    const int* tpm  = (const int*)d_in[7];
    const int E = in_sizes[4] / 2;           // 100000
    float* out = (float*)d_out;

    // workspace layout (~13.2 MB)
    unsigned short* tfb = (unsigned short*)d_ws;                        // 8 MB
    unsigned char*  tf8 = (unsigned char*)(tfb + (size_t)NROWS * DDIM); // 4 MB
    unsigned char*  wg8 = tf8 + (size_t)NROWS * DDIM;                   // 512 KB
    unsigned char*  wv8 = wg8 + (size_t)NDIM * KDIM;                    // 512 KB
    int* counts = (int*)(wv8 + (size_t)NDIM * KDIM);                    // 128 B
    unsigned short* lists = (unsigned short*)(counts + 32);             // 128 KB

    prep_all<<<dim3(4609), dim3(256), 0, stream>>>(
        tok, Wg, Wv, bp, tfb, tf8, wg8, wv8, counts, lists);
    int nLemBlocks = (E + 63) / 64;          // 1563
    fused_main<<<dim3(NLM + nLemBlocks), dim3(256), 0, stream>>>(
        tf8, wg8, wv8, Wo, edge, edge + E, out, E,
        tok, tfb, lmi, counts, lists, tpm, out + E);
}

// Round 10
// 291.259 us; speedup vs baseline: 1.3690x; 1.2282x over previous
//
#include <hip/hip_runtime.h>
#include <hip/hip_bf16.h>

typedef __bf16 bf16x8 __attribute__((ext_vector_type(8)));
typedef int   i32x8 __attribute__((ext_vector_type(8)));
typedef float f32x4 __attribute__((ext_vector_type(4)));

#define KDIM 512
#define NDIM 1024
#define DDIM 256
#define TDIM 512
#define MDIM 2048
#define NROWS 16384          // B*T type_flat rows
#define NEGV -1e10f
#define NLM 128              // lm blocks fused at the front of the main grid

__device__ __forceinline__ unsigned short f2b(float f) {
    unsigned int u = __builtin_bit_cast(unsigned int, f);
    u += 0x7fffu + ((u >> 16) & 1u);   // RNE
    return (unsigned short)(u >> 16);
}

typedef const __attribute__((address_space(1))) unsigned int* gas_p;
typedef __attribute__((address_space(3))) unsigned int* las_p;
__device__ __forceinline__ void gl2lds16(const void* g, void* l) {
    __builtin_amdgcn_global_load_lds((gas_p)g, (las_p)l, 16, 0, 0);
}

// ---------------------------------------------------------------------------
// prep_all: one launch, three roles by blockIdx.  (unchanged from R6-R9)
// ---------------------------------------------------------------------------
__global__ void prep_all(const float* __restrict__ tok,
                         const float* __restrict__ Wg,
                         const float* __restrict__ Wv,
                         const int* __restrict__ bp,
                         unsigned short* __restrict__ tfb,
                         unsigned char* __restrict__ tf8,
                         unsigned char* __restrict__ wg8,
                         unsigned char* __restrict__ wv8,
                         int* __restrict__ counts,
                         unsigned short* __restrict__ lists) {
    const int bid = blockIdx.x;
    const int tid = threadIdx.x;
    if (bid < 4096) {
        int g = (bid * 256 + tid) * 4;
        int i = g >> 8, c = g & 255;
        float4 v = *(const float4*)(tok + (size_t)i * 1024 + c);
        tfb[g + 0] = f2b(v.x);
        tfb[g + 1] = f2b(v.y);
        tfb[g + 2] = f2b(v.z);
        tfb[g + 3] = f2b(v.w);
        unsigned int p = (unsigned int)__builtin_amdgcn_cvt_pk_fp8_f32(v.x, v.y, 0, 0);
        p = (unsigned int)__builtin_amdgcn_cvt_pk_fp8_f32(v.z, v.w, (int)p, 1);
        *(unsigned int*)(tf8 + g) = p;
    } else if (bid < 4608) {
        __shared__ float tg[32][33];
        __shared__ float tv[32][33];
        int pb = bid - 4096;
        int n0 = (pb & 31) * 32, k0 = (pb >> 5) * 32;
        {
            int kk = tid >> 3, nn = (tid & 7) * 4;
            float4 g = *(const float4*)(Wg + (size_t)(k0 + kk) * NDIM + n0 + nn);
            float4 v = *(const float4*)(Wv + (size_t)(k0 + kk) * NDIM + n0 + nn);
            tg[kk][nn] = g.x; tg[kk][nn + 1] = g.y; tg[kk][nn + 2] = g.z; tg[kk][nn + 3] = g.w;
            tv[kk][nn] = v.x; tv[kk][nn + 1] = v.y; tv[kk][nn + 2] = v.z; tv[kk][nn + 3] = v.w;
        }
        __syncthreads();
        int nn2 = tid >> 3, kk2 = (tid & 7) * 4;
        unsigned int pg = (unsigned int)__builtin_amdgcn_cvt_pk_fp8_f32(
            tg[kk2][nn2], tg[kk2 + 1][nn2], 0, 0);
        pg = (unsigned int)__builtin_amdgcn_cvt_pk_fp8_f32(
            tg[kk2 + 2][nn2], tg[kk2 + 3][nn2], (int)pg, 1);
        unsigned int pv = (unsigned int)__builtin_amdgcn_cvt_pk_fp8_f32(
            tv[kk2][nn2], tv[kk2 + 1][nn2], 0, 0);
        pv = (unsigned int)__builtin_amdgcn_cvt_pk_fp8_f32(
            tv[kk2 + 2][nn2], tv[kk2 + 3][nn2], (int)pv, 1);
        *(unsigned int*)(wg8 + (size_t)(n0 + nn2) * KDIM + k0 + kk2) = pg;
        *(unsigned int*)(wv8 + (size_t)(n0 + nn2) * KDIM + k0 + kk2) = pv;
    } else {
        __shared__ int c[32];
        if (tid < 32) c[tid] = 0;
        __syncthreads();
        for (int m = tid; m < MDIM; m += 256) {
            int b = bp[m];
            int pos = atomicAdd(&c[b], 1);
            lists[b * MDIM + pos] = (unsigned short)m;
        }
        __syncthreads();
        if (tid < 32) counts[tid] = c[tid];
    }
}

// ---------------------------------------------------------------------------
// fused_main: blocks [0,NLM) = lm_preds gather-GEMM (unchanged, proven);
// blocks [NLM,..) = lemma MX-fp8 dual GEMM, M=128/block:
//   - A staged ONCE into FRAGMENT-ORDERED LDS regions (wm,mi,kc,j): 64 x 1KB.
//     DMA writes in exact read order -> reads are base+lane*16: conflict-free,
//     zero address math.  (R7's A swizzle caused 12.8M conflict cycles.)
//   - B staged per (nt,kc) into 16 fragment-ordered 1KB regions (arr,wn,ni,h),
//     16 KB single buffer; each wave stages 4 regions, all read post-barrier.
//   - wave = 64m x 32n dual-acc (64 acc regs); 16 MFMA between barriers.
// LDS = 64 KB A + 16 KB B (reduce aliases B) = exactly 80 KB -> 2 blocks/CU.
// ---------------------------------------------------------------------------
__launch_bounds__(256, 2)
__global__ void fused_main(const unsigned char* __restrict__ tf8,
                           const unsigned char* __restrict__ wg8,
                           const unsigned char* __restrict__ wv8,
                           const float* __restrict__ Wo,
                           const int* __restrict__ scope,
                           const int* __restrict__ goal,
                           float* __restrict__ outLem, int E,
                           const float* __restrict__ tok,
                           const unsigned short* __restrict__ tfb,
                           const int* __restrict__ lmi,
                           const int* __restrict__ counts,
                           const unsigned short* __restrict__ lists,
                           const int* __restrict__ tpm,
                           float* __restrict__ outP) {
    __shared__ unsigned char sA[64 * 1024];   // 64 regions x 1 KB, key (wm,mi,kc,j)
    __shared__ unsigned char sB[16 * 1024];   // 16 regions x 1 KB, key (arr,wn,ni,h)

    const int tid = threadIdx.x;
    const int lane = tid & 63;
    const int w = tid >> 6;
    const int col = lane & 15;
    const int q = lane >> 4;

    if ((int)blockIdx.x < NLM) {
        // ---------------- lm_preds gather-GEMM (R5/R6-proven) ----------------
        const int lb = blockIdx.x;
        const int b = lb & 31;
        const int t0 = (lb >> 5) * 128;
        const int cnt = counts[b];
        for (int mt = w * 16; mt < cnt; mt += 64) {
            int mc = mt + col;
            int aid = lists[b * MDIM + (mc < cnt ? mc : cnt - 1)];
            const float* arow = tok + (size_t)lmi[aid] * DDIM;
            bf16x8 af[8];
#pragma unroll
            for (int k = 0; k < 8; k++) {
                float4 lo = *(const float4*)(arow + k * 32 + q * 8);
                float4 hi = *(const float4*)(arow + k * 32 + q * 8 + 4);
                uint4 p;
                p.x = f2b(lo.x) | ((unsigned int)f2b(lo.y) << 16);
                p.y = f2b(lo.z) | ((unsigned int)f2b(lo.w) << 16);
                p.z = f2b(hi.x) | ((unsigned int)f2b(hi.y) << 16);
                p.w = f2b(hi.z) | ((unsigned int)f2b(hi.w) << 16);
                af[k] = __builtin_bit_cast(bf16x8, p);
            }
            int gm[4];
#pragma unroll
            for (int r = 0; r < 4; r++) {
                int mrow = mt + q * 4 + r;
                gm[r] = (mrow < cnt) ? (int)lists[b * MDIM + mrow] : -1;
            }
#pragma unroll
            for (int ntile = 0; ntile < 8; ntile++) {
                int t = t0 + ntile * 16 + col;
                const unsigned short* brow = tfb + (size_t)(b * TDIM + t) * DDIM;
                f32x4 acc = (f32x4){0.f, 0.f, 0.f, 0.f};
#pragma unroll
                for (int k = 0; k < 8; k++) {
                    bf16x8 bf = __builtin_bit_cast(bf16x8,
                        *(const uint4*)(brow + k * 32 + q * 8));
                    acc = __builtin_amdgcn_mfma_f32_16x16x32_bf16(af[k], bf, acc, 0, 0, 0);
                }
                int pmv = tpm[b * TDIM + t];
#pragma unroll
                for (int r = 0; r < 4; r++) {
                    if (gm[r] >= 0)
                        outP[(size_t)gm[r] * TDIM + t] = pmv ? acc[r] : NEGV;
                }
            }
        }
        return;
    }

    // ------------------------- lemma MX-fp8 GEMM -------------------------
    const int bx = blockIdx.x - NLM;
    const int etile = bx * 128;
    const int wm = w & 1;      // m-half (64 rows)
    const int wn = w >> 1;     // n-half (32 of the 64-wide n-tile)

    // ---- stage A once: 64 fragment-ordered regions, 16 per wave ----
    // region r = ((am*4 + mi)*4 + kc)*2 + j; lane (col,q) sources bytes
    // [q*32 + j*16 ..+16) of k-chunk kc for edge row am*64+mi*16+col.
#pragma unroll
    for (int i = 0; i < 16; i++) {
        int r = w * 16 + i;
        int j = r & 1, kc = (r >> 1) & 3, mi = (r >> 3) & 3, am = r >> 5;
        int row = am * 64 + mi * 16 + col;
        int e = etile + row;
        int id = (e < E) ? ((kc < 2) ? scope[e] : goal[e]) : 0;
        gl2lds16(tf8 + (size_t)id * DDIM + (kc & 1) * 128 + q * 32 + j * 16,
                 &sA[r * 1024]);
    }

    float lem[16];
#pragma unroll
    for (int i = 0; i < 16; i++) lem[i] = 0.f;

    for (int nt = 0; nt < 16; nt++) {
        const int n0 = nt * 64;
        f32x4 accG[4][2], accV[4][2];
#pragma unroll
        for (int mi = 0; mi < 4; mi++)
#pragma unroll
            for (int ni = 0; ni < 2; ni++) {
                accG[mi][ni] = (f32x4){0.f, 0.f, 0.f, 0.f};
                accV[mi][ni] = (f32x4){0.f, 0.f, 0.f, 0.f};
            }
#pragma unroll
        for (int kc = 0; kc < 4; kc++) {
            __syncthreads();                   // B readers of step s-1 done
            // stage B: 16 fragment-ordered regions, 4 per wave
            // region r = ((arr*2 + wn')*2 + ni)*2 + h
#pragma unroll
            for (int i = 0; i < 4; i++) {
                int r = w * 4 + i;
                int arr = r >> 3, wnn = (r >> 2) & 1, ni = (r >> 1) & 1, h = r & 1;
                int n = n0 + wnn * 32 + ni * 16 + col;
                const unsigned char* src = (arr ? wv8 : wg8) +
                    (size_t)n * KDIM + kc * 128 + q * 32 + h * 16;
                gl2lds16(src, &sB[r * 1024]);
            }
            __syncthreads();                   // B staged (vmcnt drain)
            // A fragments: conflict-free base+lane*16 reads
            i32x8 af[4];
#pragma unroll
            for (int mi = 0; mi < 4; mi++) {
                int rb = ((wm * 4 + mi) * 4 + kc) * 2;
                uint4 lo = *(const uint4*)(&sA[rb * 1024 + lane * 16]);
                uint4 hi = *(const uint4*)(&sA[(rb + 1) * 1024 + lane * 16]);
                af[mi] = (i32x8){(int)lo.x, (int)lo.y, (int)lo.z, (int)lo.w,
                                 (int)hi.x, (int)hi.y, (int)hi.z, (int)hi.w};
            }
#pragma unroll
            for (int ni = 0; ni < 2; ni++) {
                int rg = ((0 + wn) * 2 + ni) * 2;          // arr=0
                int rv = ((2 + wn) * 2 + ni) * 2;          // arr=1
                uint4 lo = *(const uint4*)(&sB[rg * 1024 + lane * 16]);
                uint4 hi = *(const uint4*)(&sB[(rg + 1) * 1024 + lane * 16]);
                i32x8 bg = (i32x8){(int)lo.x, (int)lo.y, (int)lo.z, (int)lo.w,
                                   (int)hi.x, (int)hi.y, (int)hi.z, (int)hi.w};
                lo = *(const uint4*)(&sB[rv * 1024 + lane * 16]);
                hi = *(const uint4*)(&sB[(rv + 1) * 1024 + lane * 16]);
                i32x8 bv = (i32x8){(int)lo.x, (int)lo.y, (int)lo.z, (int)lo.w,
                                   (int)hi.x, (int)hi.y, (int)hi.z, (int)hi.w};
#pragma unroll
                for (int mi = 0; mi < 4; mi++) {
                    accG[mi][ni] = __builtin_amdgcn_mfma_scale_f32_16x16x128_f8f6f4(
                        af[mi], bg, accG[mi][ni], 0, 0, 0, 0x7F7F7F7F, 0, 0x7F7F7F7F);
                    accV[mi][ni] = __builtin_amdgcn_mfma_scale_f32_16x16x128_f8f6f4(
                        af[mi], bv, accV[mi][ni], 0, 0, 0, 0x7F7F7F7F, 0, 0x7F7F7F7F);
                }
            }
        }
        // epilogue: lem += silu(G) * V * Wo[n]. C/D: M=q*4+r, N=col.
#pragma unroll
        for (int ni = 0; ni < 2; ni++) {
            float wo = Wo[n0 + wn * 32 + ni * 16 + col];
#pragma unroll
            for (int mi = 0; mi < 4; mi++)
#pragma unroll
                for (int r = 0; r < 4; r++) {
                    float g = accG[mi][ni][r];
                    float v = accV[mi][ni][r];
                    float s = g / (1.f + __expf(-g));
                    lem[mi * 4 + r] += s * v * wo;
                }
        }
    }
    // reduce across the 16 N-cols, then across the 2 n-wave halves
    __syncthreads();                           // before aliasing sB as sRed
    float* sRed = (float*)sB;
#pragma unroll
    for (int i = 0; i < 16; i++) {
        float v = lem[i];
        for (int off = 8; off > 0; off >>= 1) v += __shfl_xor(v, off, 16);
        if (col == 0) {
            int row = wm * 64 + (i >> 2) * 16 + q * 4 + (i & 3);
            sRed[wn * 128 + row] = v;
        }
    }
    __syncthreads();
    if (tid < 128) {
        int e = etile + tid;
        if (e < E) outLem[e] = sRed[tid] + sRed[128 + tid];
    }
}

extern "C" void kernel_launch(void* const* d_in, const int* in_sizes, int n_in,
                              void* d_out, int out_size, void* d_ws, size_t ws_size,
                              hipStream_t stream) {
    const float* tok = (const float*)d_in[0];
    const float* Wg  = (const float*)d_in[1];
    const float* Wv  = (const float*)d_in[2];
    const float* Wo  = (const float*)d_in[3];
    const int* edge = (const int*)d_in[4];
    const int* lmi  = (const int*)d_in[5];
    const int* bp   = (const int*)d_in[6];
    const int* tpm  = (const int*)d_in[7];
    const int E = in_sizes[4] / 2;           // 100000
    float* out = (float*)d_out;

    // workspace layout (~13.2 MB)
    unsigned short* tfb = (unsigned short*)d_ws;                        // 8 MB
    unsigned char*  tf8 = (unsigned char*)(tfb + (size_t)NROWS * DDIM); // 4 MB
    unsigned char*  wg8 = tf8 + (size_t)NROWS * DDIM;                   // 512 KB
    unsigned char*  wv8 = wg8 + (size_t)NDIM * KDIM;                    // 512 KB
    int* counts = (int*)(wv8 + (size_t)NDIM * KDIM);                    // 128 B
    unsigned short* lists = (unsigned short*)(counts + 32);             // 128 KB

    prep_all<<<dim3(4609), dim3(256), 0, stream>>>(
        tok, Wg, Wv, bp, tfb, tf8, wg8, wv8, counts, lists);
    int nLemBlocks = (E + 127) / 128;        // 782
    fused_main<<<dim3(NLM + nLemBlocks), dim3(256), 0, stream>>>(
        tf8, wg8, wv8, Wo, edge, edge + E, out, E,
        tok, tfb, lmi, counts, lists, tpm, out + E);
}

// Round 11
// 264.775 us; speedup vs baseline: 1.5060x; 1.1000x over previous
//
#include <hip/hip_runtime.h>
#include <hip/hip_bf16.h>

typedef __bf16 bf16x8 __attribute__((ext_vector_type(8)));
typedef int   i32x8 __attribute__((ext_vector_type(8)));
typedef float f32x4 __attribute__((ext_vector_type(4)));

#define KDIM 512
#define NDIM 1024
#define DDIM 256
#define TDIM 512
#define MDIM 2048
#define NROWS 16384          // B*T type_flat rows
#define NEGV -1e10f
#define NLM 128              // lm blocks fused at the front of the main grid
#define WARR 524288          // byte offset of V-array in permuted weights

__device__ __forceinline__ unsigned short f2b(float f) {
    unsigned int u = __builtin_bit_cast(unsigned int, f);
    u += 0x7fffu + ((u >> 16) & 1u);   // RNE
    return (unsigned short)(u >> 16);
}

typedef const __attribute__((address_space(1))) unsigned int* gas_p;
typedef __attribute__((address_space(3))) unsigned int* las_p;
__device__ __forceinline__ void gl2lds16(const void* g, void* l) {
    __builtin_amdgcn_global_load_lds((gas_p)g, (las_p)l, 16, 0, 0);
}

// ---------------------------------------------------------------------------
// prep_all: one launch, three roles by blockIdx.
//  blocks [0,4096):    type_flat -> bf16 tfb AND fp8 tf8
//  blocks [4096,4608): Wg,Wv f32 [k][n] -> fp8 in MFMA-FRAGMENT ORDER:
//      frag = ((nt*4+kc)*2+wn)*2+ni  (2 KB each; G at 0, V at +512 KB)
//      byte within frag = (q*16+col)*32 + h*16 + b   == lane*32 + h*16 + b
//  block  4608:        bucket m by bp[m] -> counts/lists
// ---------------------------------------------------------------------------
__global__ void prep_all(const float* __restrict__ tok,
                         const float* __restrict__ Wg,
                         const float* __restrict__ Wv,
                         const int* __restrict__ bp,
                         unsigned short* __restrict__ tfb,
                         unsigned char* __restrict__ tf8,
                         unsigned char* __restrict__ wp8,
                         int* __restrict__ counts,
                         unsigned short* __restrict__ lists) {
    const int bid = blockIdx.x;
    const int tid = threadIdx.x;
    if (bid < 4096) {
        int g = (bid * 256 + tid) * 4;
        int i = g >> 8, c = g & 255;
        float4 v = *(const float4*)(tok + (size_t)i * 1024 + c);
        tfb[g + 0] = f2b(v.x);
        tfb[g + 1] = f2b(v.y);
        tfb[g + 2] = f2b(v.z);
        tfb[g + 3] = f2b(v.w);
        unsigned int p = (unsigned int)__builtin_amdgcn_cvt_pk_fp8_f32(v.x, v.y, 0, 0);
        p = (unsigned int)__builtin_amdgcn_cvt_pk_fp8_f32(v.z, v.w, (int)p, 1);
        *(unsigned int*)(tf8 + g) = p;
    } else if (bid < 4608) {
        __shared__ float tg[32][33];
        __shared__ float tv[32][33];
        int pb = bid - 4096;
        int n0 = (pb & 31) * 32, k0 = (pb >> 5) * 32;
        {
            int kk = tid >> 3, nn = (tid & 7) * 4;
            float4 g = *(const float4*)(Wg + (size_t)(k0 + kk) * NDIM + n0 + nn);
            float4 v = *(const float4*)(Wv + (size_t)(k0 + kk) * NDIM + n0 + nn);
            tg[kk][nn] = g.x; tg[kk][nn + 1] = g.y; tg[kk][nn + 2] = g.z; tg[kk][nn + 3] = g.w;
            tv[kk][nn] = v.x; tv[kk][nn + 1] = v.y; tv[kk][nn + 2] = v.z; tv[kk][nn + 3] = v.w;
        }
        __syncthreads();
        int nn2 = tid >> 3, kk2 = (tid & 7) * 4;
        unsigned int pg = (unsigned int)__builtin_amdgcn_cvt_pk_fp8_f32(
            tg[kk2][nn2], tg[kk2 + 1][nn2], 0, 0);
        pg = (unsigned int)__builtin_amdgcn_cvt_pk_fp8_f32(
            tg[kk2 + 2][nn2], tg[kk2 + 3][nn2], (int)pg, 1);
        unsigned int pv = (unsigned int)__builtin_amdgcn_cvt_pk_fp8_f32(
            tv[kk2][nn2], tv[kk2 + 1][nn2], 0, 0);
        pv = (unsigned int)__builtin_amdgcn_cvt_pk_fp8_f32(
            tv[kk2 + 2][nn2], tv[kk2 + 3][nn2], (int)pv, 1);
        int n = n0 + nn2, k = k0 + kk2;
        int nt = n >> 6, wn = (n >> 5) & 1, ni = (n >> 4) & 1, cp = n & 15;
        int kc = k >> 7, rem = k & 127, qq = rem >> 5, hh = (rem >> 4) & 1, bb = rem & 15;
        int frag = ((nt * 4 + kc) * 2 + wn) * 2 + ni;
        size_t off = (size_t)frag * 2048 + (qq * 16 + cp) * 32 + hh * 16 + bb;
        *(unsigned int*)(wp8 + off) = pg;
        *(unsigned int*)(wp8 + WARR + off) = pv;
    } else {
        __shared__ int c[32];
        if (tid < 32) c[tid] = 0;
        __syncthreads();
        for (int m = tid; m < MDIM; m += 256) {
            int b = bp[m];
            int pos = atomicAdd(&c[b], 1);
            lists[b * MDIM + pos] = (unsigned short)m;
        }
        __syncthreads();
        if (tid < 32) counts[tid] = c[tid];
    }
}

// ---------------------------------------------------------------------------
// fused_main: blocks [0,NLM) = lm_preds gather-GEMM (unchanged, proven);
// blocks [NLM,..) = lemma MX-fp8 dual GEMM, BARRIER-FREE K-loop:
//   - A staged ONCE into fragment-ordered LDS (R10-proven: 64 x 1 KB regions,
//     reads are base+lane*16, 0 conflicts); single barrier after staging.
//   - B loaded DIRECTLY from fragment-ordered global (coalesced base+lane*32,
//     L2-hot 1 MB) -> NO __syncthreads in the 64-step loop; compiler pipelines
//     loads across steps with fine-grained vmcnt/lgkmcnt (no barrier drains,
//     which capped R7/R9/R10 at MfmaUtil 15-25%).  R8's direct-load failure
//     was uncoalesced addressing (lane-stride-512B), fixed by the prep layout.
//   - wave = 64m x 32n dual-acc (64 AGPRs); arch VGPRs ~120 -> no spill.
// LDS = 64 KB A + 1 KB reduce -> 2 blocks/CU.
// ---------------------------------------------------------------------------
__launch_bounds__(256, 2)
__global__ void fused_main(const unsigned char* __restrict__ tf8,
                           const unsigned char* __restrict__ wp8,
                           const float* __restrict__ Wo,
                           const int* __restrict__ scope,
                           const int* __restrict__ goal,
                           float* __restrict__ outLem, int E,
                           const float* __restrict__ tok,
                           const unsigned short* __restrict__ tfb,
                           const int* __restrict__ lmi,
                           const int* __restrict__ counts,
                           const unsigned short* __restrict__ lists,
                           const int* __restrict__ tpm,
                           float* __restrict__ outP) {
    __shared__ unsigned char sA[64 * 1024];   // 64 regions x 1 KB, key (am,mi,kc,j)
    __shared__ float sRed[256];

    const int tid = threadIdx.x;
    const int lane = tid & 63;
    const int w = tid >> 6;
    const int col = lane & 15;
    const int q = lane >> 4;

    if ((int)blockIdx.x < NLM) {
        // ---------------- lm_preds gather-GEMM (R5/R6-proven) ----------------
        const int lb = blockIdx.x;
        const int b = lb & 31;
        const int t0 = (lb >> 5) * 128;
        const int cnt = counts[b];
        for (int mt = w * 16; mt < cnt; mt += 64) {
            int mc = mt + col;
            int aid = lists[b * MDIM + (mc < cnt ? mc : cnt - 1)];
            const float* arow = tok + (size_t)lmi[aid] * DDIM;
            bf16x8 af[8];
#pragma unroll
            for (int k = 0; k < 8; k++) {
                float4 lo = *(const float4*)(arow + k * 32 + q * 8);
                float4 hi = *(const float4*)(arow + k * 32 + q * 8 + 4);
                uint4 p;
                p.x = f2b(lo.x) | ((unsigned int)f2b(lo.y) << 16);
                p.y = f2b(lo.z) | ((unsigned int)f2b(lo.w) << 16);
                p.z = f2b(hi.x) | ((unsigned int)f2b(hi.y) << 16);
                p.w = f2b(hi.z) | ((unsigned int)f2b(hi.w) << 16);
                af[k] = __builtin_bit_cast(bf16x8, p);
            }
            int gm[4];
#pragma unroll
            for (int r = 0; r < 4; r++) {
                int mrow = mt + q * 4 + r;
                gm[r] = (mrow < cnt) ? (int)lists[b * MDIM + mrow] : -1;
            }
#pragma unroll
            for (int ntile = 0; ntile < 8; ntile++) {
                int t = t0 + ntile * 16 + col;
                const unsigned short* brow = tfb + (size_t)(b * TDIM + t) * DDIM;
                f32x4 acc = (f32x4){0.f, 0.f, 0.f, 0.f};
#pragma unroll
                for (int k = 0; k < 8; k++) {
                    bf16x8 bf = __builtin_bit_cast(bf16x8,
                        *(const uint4*)(brow + k * 32 + q * 8));
                    acc = __builtin_amdgcn_mfma_f32_16x16x32_bf16(af[k], bf, acc, 0, 0, 0);
                }
                int pmv = tpm[b * TDIM + t];
#pragma unroll
                for (int r = 0; r < 4; r++) {
                    if (gm[r] >= 0)
                        outP[(size_t)gm[r] * TDIM + t] = pmv ? acc[r] : NEGV;
                }
            }
        }
        return;
    }

    // ------------------------- lemma MX-fp8 GEMM -------------------------
    const int bx = blockIdx.x - NLM;
    const int etile = bx * 128;
    const int wm = w & 1;      // m-half (64 rows)
    const int wn = w >> 1;     // n-half (32 of the 64-wide n-tile)

    // ---- stage A once: 64 fragment-ordered regions, 16 per wave (R10) ----
#pragma unroll
    for (int i = 0; i < 16; i++) {
        int r = w * 16 + i;
        int j = r & 1, kc = (r >> 1) & 3, mi = (r >> 3) & 3, am = r >> 5;
        int row = am * 64 + mi * 16 + col;
        int e = etile + row;
        int id = (e < E) ? ((kc < 2) ? scope[e] : goal[e]) : 0;
        gl2lds16(tf8 + (size_t)id * DDIM + (kc & 1) * 128 + q * 32 + j * 16,
                 &sA[r * 1024]);
    }
    __syncthreads();   // the ONLY barrier before the reduction

    float lem[16];
#pragma unroll
    for (int i = 0; i < 16; i++) lem[i] = 0.f;

    // per-lane fragment base in permuted weights
    const unsigned char* wbase = wp8 + lane * 32;

    for (int nt = 0; nt < 16; nt++) {
        f32x4 accG[4][2], accV[4][2];
#pragma unroll
        for (int mi = 0; mi < 4; mi++)
#pragma unroll
            for (int ni = 0; ni < 2; ni++) {
                accG[mi][ni] = (f32x4){0.f, 0.f, 0.f, 0.f};
                accV[mi][ni] = (f32x4){0.f, 0.f, 0.f, 0.f};
            }
#pragma unroll
        for (int kc = 0; kc < 4; kc++) {
            // B fragments: coalesced direct loads from fragment-ordered global
            i32x8 bg[2], bv[2];
#pragma unroll
            for (int ni = 0; ni < 2; ni++) {
                size_t f = (size_t)(((nt * 4 + kc) * 2 + wn) * 2 + ni) * 2048;
                uint4 lo = *(const uint4*)(wbase + f);
                uint4 hi = *(const uint4*)(wbase + f + 16);
                bg[ni] = (i32x8){(int)lo.x, (int)lo.y, (int)lo.z, (int)lo.w,
                                 (int)hi.x, (int)hi.y, (int)hi.z, (int)hi.w};
                lo = *(const uint4*)(wbase + WARR + f);
                hi = *(const uint4*)(wbase + WARR + f + 16);
                bv[ni] = (i32x8){(int)lo.x, (int)lo.y, (int)lo.z, (int)lo.w,
                                 (int)hi.x, (int)hi.y, (int)hi.z, (int)hi.w};
            }
            // A fragments: conflict-free base+lane*16 LDS reads
#pragma unroll
            for (int mi = 0; mi < 4; mi++) {
                int rb = ((wm * 4 + mi) * 4 + kc) * 2;
                uint4 lo = *(const uint4*)(&sA[rb * 1024 + lane * 16]);
                uint4 hi = *(const uint4*)(&sA[(rb + 1) * 1024 + lane * 16]);
                i32x8 af = (i32x8){(int)lo.x, (int)lo.y, (int)lo.z, (int)lo.w,
                                   (int)hi.x, (int)hi.y, (int)hi.z, (int)hi.w};
#pragma unroll
                for (int ni = 0; ni < 2; ni++) {
                    accG[mi][ni] = __builtin_amdgcn_mfma_scale_f32_16x16x128_f8f6f4(
                        af, bg[ni], accG[mi][ni], 0, 0, 0, 0x7F7F7F7F, 0, 0x7F7F7F7F);
                    accV[mi][ni] = __builtin_amdgcn_mfma_scale_f32_16x16x128_f8f6f4(
                        af, bv[ni], accV[mi][ni], 0, 0, 0, 0x7F7F7F7F, 0, 0x7F7F7F7F);
                }
            }
        }
        // epilogue: lem += silu(G) * V * Wo[n]. C/D: M=q*4+r, N=col.
#pragma unroll
        for (int ni = 0; ni < 2; ni++) {
            float wo = Wo[nt * 64 + wn * 32 + ni * 16 + col];
#pragma unroll
            for (int mi = 0; mi < 4; mi++)
#pragma unroll
                for (int r = 0; r < 4; r++) {
                    float g = accG[mi][ni][r];
                    float v = accV[mi][ni][r];
                    float s = g / (1.f + __expf(-g));
                    lem[mi * 4 + r] += s * v * wo;
                }
        }
    }
    // reduce across the 16 N-cols, then across the 2 n-wave halves
#pragma unroll
    for (int i = 0; i < 16; i++) {
        float v = lem[i];
        for (int off = 8; off > 0; off >>= 1) v += __shfl_xor(v, off, 16);
        if (col == 0) {
            int row = wm * 64 + (i >> 2) * 16 + q * 4 + (i & 3);
            sRed[wn * 128 + row] = v;
        }
    }
    __syncthreads();
    if (tid < 128) {
        int e = etile + tid;
        if (e < E) outLem[e] = sRed[tid] + sRed[128 + tid];
    }
}

extern "C" void kernel_launch(void* const* d_in, const int* in_sizes, int n_in,
                              void* d_out, int out_size, void* d_ws, size_t ws_size,
                              hipStream_t stream) {
    const float* tok = (const float*)d_in[0];
    const float* Wg  = (const float*)d_in[1];
    const float* Wv  = (const float*)d_in[2];
    const float* Wo  = (const float*)d_in[3];
    const int* edge = (const int*)d_in[4];
    const int* lmi  = (const int*)d_in[5];
    const int* bp   = (const int*)d_in[6];
    const int* tpm  = (const int*)d_in[7];
    const int E = in_sizes[4] / 2;           // 100000
    float* out = (float*)d_out;

    // workspace layout (~13.2 MB)
    unsigned short* tfb = (unsigned short*)d_ws;                        // 8 MB
    unsigned char*  tf8 = (unsigned char*)(tfb + (size_t)NROWS * DDIM); // 4 MB
    unsigned char*  wp8 = tf8 + (size_t)NROWS * DDIM;                   // 1 MB (G+V)
    int* counts = (int*)(wp8 + 2 * WARR / 1);                           // after 1 MB
    unsigned short* lists = (unsigned short*)(counts + 32);             // 128 KB

    prep_all<<<dim3(4609), dim3(256), 0, stream>>>(
        tok, Wg, Wv, bp, tfb, tf8, wp8, counts, lists);
    int nLemBlocks = (E + 127) / 128;        // 782
    fused_main<<<dim3(NLM + nLemBlocks), dim3(256), 0, stream>>>(
        tf8, wp8, Wo, edge, edge + E, out, E,
        tok, tfb, lmi, counts, lists, tpm, out + E);
}

// Round 12
// 248.670 us; speedup vs baseline: 1.6035x; 1.0648x over previous
//
#include <hip/hip_runtime.h>
#include <hip/hip_bf16.h>

typedef __bf16 bf16x8 __attribute__((ext_vector_type(8)));
typedef int   i32x8 __attribute__((ext_vector_type(8)));
typedef float f32x4 __attribute__((ext_vector_type(4)));

#define KDIM 512
#define NDIM 1024
#define DDIM 256
#define TDIM 512
#define MDIM 2048
#define NROWS 16384          // B*T type_flat rows
#define NEGV -1e10f
#define NLM 128              // lm blocks fused at the front of the main grid
#define WARR 524288          // byte offset of V-array in permuted weights

__device__ __forceinline__ unsigned short f2b(float f) {
    unsigned int u = __builtin_bit_cast(unsigned int, f);
    u += 0x7fffu + ((u >> 16) & 1u);   // RNE
    return (unsigned short)(u >> 16);
}

typedef const __attribute__((address_space(1))) unsigned int* gas_p;
typedef __attribute__((address_space(3))) unsigned int* las_p;
__device__ __forceinline__ void gl2lds16(const void* g, void* l) {
    __builtin_amdgcn_global_load_lds((gas_p)g, (las_p)l, 16, 0, 0);
}

// ---------------------------------------------------------------------------
// prep_all: one launch, three roles by blockIdx.  (unchanged from R11)
// ---------------------------------------------------------------------------
__global__ void prep_all(const float* __restrict__ tok,
                         const float* __restrict__ Wg,
                         const float* __restrict__ Wv,
                         const int* __restrict__ bp,
                         unsigned short* __restrict__ tfb,
                         unsigned char* __restrict__ tf8,
                         unsigned char* __restrict__ wp8,
                         int* __restrict__ counts,
                         unsigned short* __restrict__ lists) {
    const int bid = blockIdx.x;
    const int tid = threadIdx.x;
    if (bid < 4096) {
        int g = (bid * 256 + tid) * 4;
        int i = g >> 8, c = g & 255;
        float4 v = *(const float4*)(tok + (size_t)i * 1024 + c);
        tfb[g + 0] = f2b(v.x);
        tfb[g + 1] = f2b(v.y);
        tfb[g + 2] = f2b(v.z);
        tfb[g + 3] = f2b(v.w);
        unsigned int p = (unsigned int)__builtin_amdgcn_cvt_pk_fp8_f32(v.x, v.y, 0, 0);
        p = (unsigned int)__builtin_amdgcn_cvt_pk_fp8_f32(v.z, v.w, (int)p, 1);
        *(unsigned int*)(tf8 + g) = p;
    } else if (bid < 4608) {
        __shared__ float tg[32][33];
        __shared__ float tv[32][33];
        int pb = bid - 4096;
        int n0 = (pb & 31) * 32, k0 = (pb >> 5) * 32;
        {
            int kk = tid >> 3, nn = (tid & 7) * 4;
            float4 g = *(const float4*)(Wg + (size_t)(k0 + kk) * NDIM + n0 + nn);
            float4 v = *(const float4*)(Wv + (size_t)(k0 + kk) * NDIM + n0 + nn);
            tg[kk][nn] = g.x; tg[kk][nn + 1] = g.y; tg[kk][nn + 2] = g.z; tg[kk][nn + 3] = g.w;
            tv[kk][nn] = v.x; tv[kk][nn + 1] = v.y; tv[kk][nn + 2] = v.z; tv[kk][nn + 3] = v.w;
        }
        __syncthreads();
        int nn2 = tid >> 3, kk2 = (tid & 7) * 4;
        unsigned int pg = (unsigned int)__builtin_amdgcn_cvt_pk_fp8_f32(
            tg[kk2][nn2], tg[kk2 + 1][nn2], 0, 0);
        pg = (unsigned int)__builtin_amdgcn_cvt_pk_fp8_f32(
            tg[kk2 + 2][nn2], tg[kk2 + 3][nn2], (int)pg, 1);
        unsigned int pv = (unsigned int)__builtin_amdgcn_cvt_pk_fp8_f32(
            tv[kk2][nn2], tv[kk2 + 1][nn2], 0, 0);
        pv = (unsigned int)__builtin_amdgcn_cvt_pk_fp8_f32(
            tv[kk2 + 2][nn2], tv[kk2 + 3][nn2], (int)pv, 1);
        int n = n0 + nn2, k = k0 + kk2;
        int nt = n >> 6, wn = (n >> 5) & 1, ni = (n >> 4) & 1, cp = n & 15;
        int kc = k >> 7, rem = k & 127, qq = rem >> 5, hh = (rem >> 4) & 1, bb = rem & 15;
        int frag = ((nt * 4 + kc) * 2 + wn) * 2 + ni;
        size_t off = (size_t)frag * 2048 + (qq * 16 + cp) * 32 + hh * 16 + bb;
        *(unsigned int*)(wp8 + off) = pg;
        *(unsigned int*)(wp8 + WARR + off) = pv;
    } else {
        __shared__ int c[32];
        if (tid < 32) c[tid] = 0;
        __syncthreads();
        for (int m = tid; m < MDIM; m += 256) {
            int b = bp[m];
            int pos = atomicAdd(&c[b], 1);
            lists[b * MDIM + pos] = (unsigned short)m;
        }
        __syncthreads();
        if (tid < 32) counts[tid] = c[tid];
    }
}

// ---------------------------------------------------------------------------
// fused_main: blocks [0,NLM) = lm_preds gather-GEMM (unchanged, proven);
// blocks [NLM,..) = lemma MX-fp8 dual GEMM, barrier-free K-loop (R11) plus:
//   - B register DOUBLE-BUFFER: step s+1's 4 i32x8 fragments load while
//     step s's 16 MFMAs run (one-full-step distance covers ~200cyc L2 lat).
//     Overrun preload at the last step reads into lists region (harmless).
//   - epilogue silu uses v_rcp (rcpf) instead of IEEE div (was ~10 VALU ops
//     + 2 transcendental per element x 512 elements/thread — VALUBusy 33%
//     exceeded MfmaUtil 24% in R11).
// LDS = 64 KB A + 1 KB reduce -> 2 blocks/CU; regs ~185 < 256 (no spill).
// ---------------------------------------------------------------------------
__launch_bounds__(256, 2)
__global__ void fused_main(const unsigned char* __restrict__ tf8,
                           const unsigned char* __restrict__ wp8,
                           const float* __restrict__ Wo,
                           const int* __restrict__ scope,
                           const int* __restrict__ goal,
                           float* __restrict__ outLem, int E,
                           const float* __restrict__ tok,
                           const unsigned short* __restrict__ tfb,
                           const int* __restrict__ lmi,
                           const int* __restrict__ counts,
                           const unsigned short* __restrict__ lists,
                           const int* __restrict__ tpm,
                           float* __restrict__ outP) {
    __shared__ unsigned char sA[64 * 1024];   // 64 regions x 1 KB, key (am,mi,kc,j)
    __shared__ float sRed[256];

    const int tid = threadIdx.x;
    const int lane = tid & 63;
    const int w = tid >> 6;
    const int col = lane & 15;
    const int q = lane >> 4;

    if ((int)blockIdx.x < NLM) {
        // ---------------- lm_preds gather-GEMM (R5/R6-proven) ----------------
        const int lb = blockIdx.x;
        const int b = lb & 31;
        const int t0 = (lb >> 5) * 128;
        const int cnt = counts[b];
        for (int mt = w * 16; mt < cnt; mt += 64) {
            int mc = mt + col;
            int aid = lists[b * MDIM + (mc < cnt ? mc : cnt - 1)];
            const float* arow = tok + (size_t)lmi[aid] * DDIM;
            bf16x8 af[8];
#pragma unroll
            for (int k = 0; k < 8; k++) {
                float4 lo = *(const float4*)(arow + k * 32 + q * 8);
                float4 hi = *(const float4*)(arow + k * 32 + q * 8 + 4);
                uint4 p;
                p.x = f2b(lo.x) | ((unsigned int)f2b(lo.y) << 16);
                p.y = f2b(lo.z) | ((unsigned int)f2b(lo.w) << 16);
                p.z = f2b(hi.x) | ((unsigned int)f2b(hi.y) << 16);
                p.w = f2b(hi.z) | ((unsigned int)f2b(hi.w) << 16);
                af[k] = __builtin_bit_cast(bf16x8, p);
            }
            int gm[4];
#pragma unroll
            for (int r = 0; r < 4; r++) {
                int mrow = mt + q * 4 + r;
                gm[r] = (mrow < cnt) ? (int)lists[b * MDIM + mrow] : -1;
            }
#pragma unroll
            for (int ntile = 0; ntile < 8; ntile++) {
                int t = t0 + ntile * 16 + col;
                const unsigned short* brow = tfb + (size_t)(b * TDIM + t) * DDIM;
                f32x4 acc = (f32x4){0.f, 0.f, 0.f, 0.f};
#pragma unroll
                for (int k = 0; k < 8; k++) {
                    bf16x8 bf = __builtin_bit_cast(bf16x8,
                        *(const uint4*)(brow + k * 32 + q * 8));
                    acc = __builtin_amdgcn_mfma_f32_16x16x32_bf16(af[k], bf, acc, 0, 0, 0);
                }
                int pmv = tpm[b * TDIM + t];
#pragma unroll
                for (int r = 0; r < 4; r++) {
                    if (gm[r] >= 0)
                        outP[(size_t)gm[r] * TDIM + t] = pmv ? acc[r] : NEGV;
                }
            }
        }
        return;
    }

    // ------------------------- lemma MX-fp8 GEMM -------------------------
    const int bx = blockIdx.x - NLM;
    const int etile = bx * 128;
    const int wm = w & 1;      // m-half (64 rows)
    const int wn = w >> 1;     // n-half (32 of the 64-wide n-tile)

    // ---- stage A once: 64 fragment-ordered regions, 16 per wave (R10) ----
#pragma unroll
    for (int i = 0; i < 16; i++) {
        int r = w * 16 + i;
        int j = r & 1, kc = (r >> 1) & 3, mi = (r >> 3) & 3, am = r >> 5;
        int row = am * 64 + mi * 16 + col;
        int e = etile + row;
        int id = (e < E) ? ((kc < 2) ? scope[e] : goal[e]) : 0;
        gl2lds16(tf8 + (size_t)id * DDIM + (kc & 1) * 128 + q * 32 + j * 16,
                 &sA[r * 1024]);
    }
    __syncthreads();   // the ONLY barrier before the reduction

    float lem[16];
#pragma unroll
    for (int i = 0; i < 16; i++) lem[i] = 0.f;

    // per-lane fragment base in permuted weights
    const unsigned char* wbase = wp8 + lane * 32;

    // B fragment loader: step index s = nt*4 + kc  (s can overrun to 64:
    // reads land in counts/lists region — allocated, never used)
#define LOADB(s, buf)                                                          \
    {                                                                          \
        _Pragma("unroll")                                                      \
        for (int ni_ = 0; ni_ < 2; ni_++) {                                    \
            size_t f_ = (size_t)(((s) * 2 + wn) * 2 + ni_) * 2048;             \
            uint4 lo_ = *(const uint4*)(wbase + f_);                           \
            uint4 hi_ = *(const uint4*)(wbase + f_ + 16);                      \
            bgb[buf][ni_] = (i32x8){(int)lo_.x, (int)lo_.y, (int)lo_.z,        \
                (int)lo_.w, (int)hi_.x, (int)hi_.y, (int)hi_.z, (int)hi_.w};   \
            lo_ = *(const uint4*)(wbase + WARR + f_);                          \
            hi_ = *(const uint4*)(wbase + WARR + f_ + 16);                     \
            bvb[buf][ni_] = (i32x8){(int)lo_.x, (int)lo_.y, (int)lo_.z,        \
                (int)lo_.w, (int)hi_.x, (int)hi_.y, (int)hi_.z, (int)hi_.w};   \
        }                                                                      \
    }

    i32x8 bgb[2][2], bvb[2][2];
    LOADB(0, 0)

    for (int nt = 0; nt < 16; nt++) {
        f32x4 accG[4][2], accV[4][2];
#pragma unroll
        for (int mi = 0; mi < 4; mi++)
#pragma unroll
            for (int ni = 0; ni < 2; ni++) {
                accG[mi][ni] = (f32x4){0.f, 0.f, 0.f, 0.f};
                accV[mi][ni] = (f32x4){0.f, 0.f, 0.f, 0.f};
            }
#pragma unroll
        for (int kc = 0; kc < 4; kc++) {
            const int cur = kc & 1, nxt = cur ^ 1;
            LOADB(nt * 4 + kc + 1, nxt)        // prefetch next step's B
            // A fragments: conflict-free base+lane*16 LDS reads
#pragma unroll
            for (int mi = 0; mi < 4; mi++) {
                int rb = ((wm * 4 + mi) * 4 + kc) * 2;
                uint4 lo = *(const uint4*)(&sA[rb * 1024 + lane * 16]);
                uint4 hi = *(const uint4*)(&sA[(rb + 1) * 1024 + lane * 16]);
                i32x8 af = (i32x8){(int)lo.x, (int)lo.y, (int)lo.z, (int)lo.w,
                                   (int)hi.x, (int)hi.y, (int)hi.z, (int)hi.w};
#pragma unroll
                for (int ni = 0; ni < 2; ni++) {
                    accG[mi][ni] = __builtin_amdgcn_mfma_scale_f32_16x16x128_f8f6f4(
                        af, bgb[cur][ni], accG[mi][ni], 0, 0, 0,
                        0x7F7F7F7F, 0, 0x7F7F7F7F);
                    accV[mi][ni] = __builtin_amdgcn_mfma_scale_f32_16x16x128_f8f6f4(
                        af, bvb[cur][ni], accV[mi][ni], 0, 0, 0,
                        0x7F7F7F7F, 0, 0x7F7F7F7F);
                }
            }
        }
        // epilogue: lem += silu(G)*V*Wo[n].  rcpf not IEEE div (R11 lesson).
#pragma unroll
        for (int ni = 0; ni < 2; ni++) {
            float wo = Wo[nt * 64 + wn * 32 + ni * 16 + col];
#pragma unroll
            for (int mi = 0; mi < 4; mi++)
#pragma unroll
                for (int r = 0; r < 4; r++) {
                    float g = accG[mi][ni][r];
                    float v = accV[mi][ni][r];
                    float s = g * __builtin_amdgcn_rcpf(1.f + __expf(-g));
                    lem[mi * 4 + r] += s * v * wo;
                }
        }
    }
    // reduce across the 16 N-cols, then across the 2 n-wave halves
#pragma unroll
    for (int i = 0; i < 16; i++) {
        float v = lem[i];
        for (int off = 8; off > 0; off >>= 1) v += __shfl_xor(v, off, 16);
        if (col == 0) {
            int row = wm * 64 + (i >> 2) * 16 + q * 4 + (i & 3);
            sRed[wn * 128 + row] = v;
        }
    }
    __syncthreads();
    if (tid < 128) {
        int e = etile + tid;
        if (e < E) outLem[e] = sRed[tid] + sRed[128 + tid];
    }
}

extern "C" void kernel_launch(void* const* d_in, const int* in_sizes, int n_in,
                              void* d_out, int out_size, void* d_ws, size_t ws_size,
                              hipStream_t stream) {
    const float* tok = (const float*)d_in[0];
    const float* Wg  = (const float*)d_in[1];
    const float* Wv  = (const float*)d_in[2];
    const float* Wo  = (const float*)d_in[3];
    const int* edge = (const int*)d_in[4];
    const int* lmi  = (const int*)d_in[5];
    const int* bp   = (const int*)d_in[6];
    const int* tpm  = (const int*)d_in[7];
    const int E = in_sizes[4] / 2;           // 100000
    float* out = (float*)d_out;

    // workspace layout (~13.2 MB)
    unsigned short* tfb = (unsigned short*)d_ws;                        // 8 MB
    unsigned char*  tf8 = (unsigned char*)(tfb + (size_t)NROWS * DDIM); // 4 MB
    unsigned char*  wp8 = tf8 + (size_t)NROWS * DDIM;                   // 1 MB (G+V)
    int* counts = (int*)(wp8 + 2 * WARR);                               // after 1 MB
    unsigned short* lists = (unsigned short*)(counts + 32);             // 128 KB

    prep_all<<<dim3(4609), dim3(256), 0, stream>>>(
        tok, Wg, Wv, bp, tfb, tf8, wp8, counts, lists);
    int nLemBlocks = (E + 127) / 128;        // 782
    fused_main<<<dim3(NLM + nLemBlocks), dim3(256), 0, stream>>>(
        tf8, wp8, Wo, edge, edge + E, out, E,
        tok, tfb, lmi, counts, lists, tpm, out + E);
}